// Round 3
// baseline (280.601 us; speedup 1.0000x reference)
//
#include <hip/hip_runtime.h>
#include <math.h>

// Problem constants: B=1, CIN=COUT=32, KS=3 (K=27), D=32, H=W=64, stride=1, pad=1, dil=1
#define DD 32
#define HH 64
#define WW 64
#define CSTRIDE (DD * HH * WW)   // 131072
#define NPOS (DD * HH * WW)

typedef __attribute__((ext_vector_type(8))) short  short8;   // 8 bf16 (4 VGPRs) MFMA A/B frag
typedef __attribute__((ext_vector_type(4))) float  float4v;  // MFMA C/D frag
typedef __attribute__((ext_vector_type(2))) unsigned uint2v;

__device__ __forceinline__ float bf2f(unsigned short u) {
    unsigned v = ((unsigned)u) << 16;
    return __builtin_bit_cast(float, v);
}
__device__ __forceinline__ float bf2f_lo(unsigned u) {       // low bf16 of a dword
    return __builtin_bit_cast(float, u << 16);
}
__device__ __forceinline__ float bf2f_hi(unsigned u) {       // high bf16 of a dword
    return __builtin_bit_cast(float, u & 0xFFFF0000u);
}
__device__ __forceinline__ unsigned short f2bf(float f) {
    unsigned u = __builtin_bit_cast(unsigned, f);
    u = u + 0x7FFFu + ((u >> 16) & 1u);        // round-to-nearest-even
    return (unsigned short)(u >> 16);
}

// ---------------------------------------------------------------------------
// prep_all: one launch does both weight swizzles and the x transpose.
//   blocks [0,128):    xT[pos][ci] bf16, 4 pos per thread (float4 loads,
//                      256 B contiguous stores per thread).
//   blocks [128,614):  wAc / wAe per-lane MFMA A-fragment swizzle.
// ---------------------------------------------------------------------------
__global__ __launch_bounds__(256) void prep_all(
    const float* __restrict__ x,
    const float* __restrict__ w_off, const float* __restrict__ w_mask,
    const float* __restrict__ w,
    unsigned short* __restrict__ xT,
    unsigned short* __restrict__ wAc, unsigned short* __restrict__ wAe)
{
    int bid = blockIdx.x;
    if (bid < 128) {
        int t    = bid * 256 + threadIdx.x;        // 0..32767
        int pos0 = t * 4;
#pragma unroll
        for (int o = 0; o < 4; o++) {              // channel octet
            float4 rows[8];
#pragma unroll
            for (int i = 0; i < 8; i++)
                rows[i] = *(const float4*)(x + (o * 8 + i) * CSTRIDE + pos0);
#pragma unroll
            for (int p = 0; p < 4; p++) {
                unsigned short tmp[8] __attribute__((aligned(16)));
                tmp[0] = f2bf(rows[0][p]); tmp[1] = f2bf(rows[1][p]);
                tmp[2] = f2bf(rows[2][p]); tmp[3] = f2bf(rows[3][p]);
                tmp[4] = f2bf(rows[4][p]); tmp[5] = f2bf(rows[5][p]);
                tmp[6] = f2bf(rows[6][p]); tmp[7] = f2bf(rows[7][p]);
                *(short8*)(xT + (size_t)(pos0 + p) * 32 + o * 8) = *(const short8*)tmp;
            }
        }
    } else {
        int i = (bid - 128) * 256 + threadIdx.x;
        if (i < 27 * 7 * 64 * 8) {                       // 96768: conv weights
            int j    = i & 7;
            int lane = (i >> 3) & 63;
            int fm   = i >> 9;
            int mt   = fm % 7;
            int tap  = fm / 7;
            int ch   = mt * 16 + (lane & 15);
            int ci   = (lane >> 4) * 8 + j;
            float v = 0.f;
            if (ch < 81)       v = w_off[(ch * 32 + ci) * 27 + tap];
            else if (ch < 108) v = w_mask[((ch - 81) * 32 + ci) * 27 + tap];
            wAc[i] = f2bf(v);
        } else if (i < 96768 + 27 * 2 * 64 * 8) {        // + 27648: einsum weights
            int i2   = i - 96768;
            int j    = i2 & 7;
            int lane = (i2 >> 3) & 63;
            int fm   = i2 >> 9;
            int mt   = fm % 2;
            int tap  = fm / 2;
            int co   = mt * 16 + (lane & 15);
            int ci   = (lane >> 4) * 8 + j;
            wAe[i2] = f2bf(w[(co * 32 + ci) * 27 + tap]);
        }
    }
}

// ---------------------------------------------------------------------------
// Main fused kernel. Block = 256 = 4 waves, one block per (d,h) row.
// Wave wv owns w-tile [wv*16, wv*16+16); lane = (q<<4)|wl, q=ci-octet, wl=w.
// No barriers: each wave's LDS columns are private.
//
// Phase 1 (conv): D[ch 112][w 16] via 16x16x32 bf16 MFMA; results go to LDS
//   as bf16 in tap-major layout offm16[wcol][4*tap + {oz,oy,ox,m}] so phase 2
//   fetches a whole tap with one ds_read_b64.
// Phase 2 (sample+einsum): 8 corner gathers of 16B (8 channels each) kept
//   concurrently in flight (launch_bounds gives the VGPR headroom); corner
//   weights computed after load issue to overlap latency; sampled octet is
//   directly the einsum MFMA B-frag.
// ---------------------------------------------------------------------------
__global__ __launch_bounds__(256, 4) void deform_mfma_kernel(
    const unsigned short* __restrict__ xT,
    const unsigned short* __restrict__ wAc,
    const unsigned short* __restrict__ wAe,
    const float* __restrict__ b_off, const float* __restrict__ b_mask,
    const float* __restrict__ bias, float* __restrict__ out)
{
    __shared__ unsigned short offm16[64 * 108];   // 13824 B, [wcol][4*tap+comp]

    const int t    = threadIdx.x;
    const int lane = t & 63;
    const int wv   = t >> 6;
    const int wl   = lane & 15;
    const int q    = lane >> 4;
    const int d    = blockIdx.x >> 6;
    const int h    = blockIdx.x & 63;
    const int wcol = wv * 16 + wl;

    // ---------------- Phase 1: offset/mask conv via MFMA ----------------
    float4v acc[7];
#pragma unroll
    for (int mt = 0; mt < 7; mt++) acc[mt] = (float4v){0.f, 0.f, 0.f, 0.f};

    for (int tap = 0; tap < 27; tap++) {
        int kz = tap / 9, ky = (tap / 3) % 3, kx = tap % 3;
        int z = d + kz - 1, y = h + ky - 1;
        if ((unsigned)z >= (unsigned)DD || (unsigned)y >= (unsigned)HH)
            continue;                             // uniform: padded plane = 0
        int wx  = wcol + kx - 1;
        bool ok = (unsigned)wx < (unsigned)WW;    // per-lane only at w edges
        int pos = (z * HH + y) * WW + (ok ? wx : 0);

        short8 b = *(const short8*)(xT + (size_t)pos * 32 + q * 8);
        if (!ok) b = (short8)0;                   // zero-pad columns

        const unsigned short* ap = wAc + (size_t)(tap * 7 * 64 + lane) * 8;
#pragma unroll
        for (int mt = 0; mt < 7; mt++) {
            short8 a = *(const short8*)(ap + mt * 64 * 8);
            acc[mt] = __builtin_amdgcn_mfma_f32_16x16x32_bf16(a, b, acc[mt], 0, 0, 0);
        }
    }

    // epilogue: bias + sigmoid(mask) -> bf16 LDS, tap-major.
    // C/D layout: col = lane&15 (w), row = q*4 + r (+16*mt) (conv channel).
#pragma unroll
    for (int mt = 0; mt < 7; mt++) {
#pragma unroll
        for (int r = 0; r < 4; r++) {
            int ch = mt * 16 + q * 4 + r;
            if (ch < 108) {
                int comp = ch / 27;               // 0=oz 1=oy 2=ox 3=mask
                int tap  = ch - comp * 27;
                float v = acc[mt][r] + (comp < 3 ? b_off[ch] : b_mask[tap]);
                if (comp == 3) v = 1.f / (1.f + __expf(-v));
                offm16[wcol * 108 + 4 * tap + comp] = f2bf(v);
            }
        }
    }
    // no __syncthreads(): each wave reads back only columns it wrote.

    // ---------------- Phase 2: deformable sampling + einsum MFMA ----------------
    float4v acc2[2];
    acc2[0] = (float4v){0.f, 0.f, 0.f, 0.f};
    acc2[1] = (float4v){0.f, 0.f, 0.f, 0.f};

    const unsigned short* omp = offm16 + wcol * 108;
    uint2v om = *(const uint2v*)omp;              // tap 0: {oz,oy | ox,m}

    for (int tap = 0; tap < 27; tap++) {
        uint2v omn;
        if (tap < 26) omn = *(const uint2v*)(omp + 4 * (tap + 1));  // prefetch

        int kz = tap / 9, ky = (tap / 3) % 3, kx = tap % 3;
        float oz = bf2f_lo(om.x), oy = bf2f_hi(om.x);
        float ox = bf2f_lo(om.y), m  = bf2f_hi(om.y);

        float zc = (float)(d + kz - 1) + oz;
        float yc = (float)(h + ky - 1) + oy;
        float xc = (float)(wcol + kx - 1) + ox;
        float zf = floorf(zc), yf = floorf(yc), xf = floorf(xc);
        int z0 = (int)zf, y0 = (int)yf, x0 = (int)xf;

        // clamped corner indices -> addresses, then ISSUE LOADS first
        int iz0 = min(max(z0, 0), DD - 1), iz1 = min(max(z0 + 1, 0), DD - 1);
        int iy0 = min(max(y0, 0), HH - 1), iy1 = min(max(y0 + 1, 0), HH - 1);
        int ix0 = min(max(x0, 0), WW - 1), ix1 = min(max(x0 + 1, 0), WW - 1);
        int o00 = (iz0 * HH + iy0) * WW, o01 = (iz0 * HH + iy1) * WW;
        int o10 = (iz1 * HH + iy0) * WW, o11 = (iz1 * HH + iy1) * WW;

        int ofs[8];
        ofs[0] = o00 + ix0; ofs[1] = o00 + ix1; ofs[2] = o01 + ix0; ofs[3] = o01 + ix1;
        ofs[4] = o10 + ix0; ofs[5] = o10 + ix1; ofs[6] = o11 + ix0; ofs[7] = o11 + ix1;

        short8 cnr[8];
#pragma unroll
        for (int c = 0; c < 8; c++)
            cnr[c] = *(const short8*)(xT + (size_t)ofs[c] * 32 + q * 8);

        // corner weights AFTER load issue (overlaps gather latency)
        float fz = zc - zf, fy = yc - yf, fx = xc - xf;
        float wz0 = (z0 >= 0 && z0 < DD)         ? (1.f - fz) : 0.f;
        float wz1 = (z0 + 1 >= 0 && z0 + 1 < DD) ? fz         : 0.f;
        float wy0 = (y0 >= 0 && y0 < HH)         ? (1.f - fy) : 0.f;
        float wy1 = (y0 + 1 >= 0 && y0 + 1 < HH) ? fy         : 0.f;
        float wx0 = (x0 >= 0 && x0 < WW)         ? (1.f - fx) : 0.f;
        float wx1 = (x0 + 1 >= 0 && x0 + 1 < WW) ? fx         : 0.f;

        float cw[8];
        float mz0 = m * wz0, mz1 = m * wz1;
        float a00 = mz0 * wy0, a01 = mz0 * wy1, a10 = mz1 * wy0, a11 = mz1 * wy1;
        cw[0] = a00 * wx0; cw[1] = a00 * wx1; cw[2] = a01 * wx0; cw[3] = a01 * wx1;
        cw[4] = a10 * wx0; cw[5] = a10 * wx1; cw[6] = a11 * wx0; cw[7] = a11 * wx1;

        float v[8];
#pragma unroll
        for (int j = 0; j < 8; j++)
            v[j] = cw[0] * bf2f((unsigned short)cnr[0][j]);
#pragma unroll
        for (int c = 1; c < 8; c++) {
            float cwc = cw[c];
#pragma unroll
            for (int j = 0; j < 8; j++)
                v[j] = fmaf(cwc, bf2f((unsigned short)cnr[c][j]), v[j]);
        }

        // pack sampled octet -> einsum B-frag; 2 MFMAs accumulate D[co32][w16]
        short8 bfr;
#pragma unroll
        for (int j = 0; j < 8; j++) bfr[j] = (short)f2bf(v[j]);

        const unsigned short* aep = wAe + (size_t)(tap * 2 * 64 + lane) * 8;
        short8 a0 = *(const short8*)(aep);
        short8 a1 = *(const short8*)(aep + 64 * 8);
        acc2[0] = __builtin_amdgcn_mfma_f32_16x16x32_bf16(a0, bfr, acc2[0], 0, 0, 0);
        acc2[1] = __builtin_amdgcn_mfma_f32_16x16x32_bf16(a1, bfr, acc2[1], 0, 0, 0);

        om = omn;
    }

    // ---------------- Epilogue: C/D layout -> global ----------------
    int sp = (d * HH + h) * WW + wcol;
#pragma unroll
    for (int mt = 0; mt < 2; mt++) {
#pragma unroll
        for (int r = 0; r < 4; r++) {
            int co = mt * 16 + q * 4 + r;
            out[co * CSTRIDE + sp] = acc2[mt][r] + bias[co];
        }
    }
}

// ---------------------------------------------------------------------------
extern "C" void kernel_launch(void* const* d_in, const int* in_sizes, int n_in,
                              void* d_out, int out_size, void* d_ws, size_t ws_size,
                              hipStream_t stream) {
    const float* x      = (const float*)d_in[0];
    const float* w_off  = (const float*)d_in[1];
    const float* b_off  = (const float*)d_in[2];
    const float* w_mask = (const float*)d_in[3];
    const float* b_mask = (const float*)d_in[4];
    const float* w      = (const float*)d_in[5];
    const float* b      = (const float*)d_in[6];
    float* out = (float*)d_out;

    // workspace: xT 8,388,608 B | wAc 193,536 B | wAe 55,296 B
    unsigned short* xT  = (unsigned short*)d_ws;
    unsigned short* wAc = xT + (size_t)NPOS * 32;
    unsigned short* wAe = wAc + 27 * 7 * 64 * 8;

    hipLaunchKernelGGL(prep_all, dim3(128 + 486), dim3(256), 0, stream,
                       x, w_off, w_mask, w, xT, wAc, wAe);
    hipLaunchKernelGGL(deform_mfma_kernel, dim3(DD * HH), dim3(256), 0, stream,
                       xT, wAc, wAe, b_off, b_mask, b, out);
}